// Round 4
// baseline (465.433 us; speedup 1.0000x reference)
//
#include <hip/hip_runtime.h>
#include <cstdint>
#include <cstddef>

// ---------------- types / helpers ----------------
typedef __attribute__((ext_vector_type(8))) __bf16 bf16x8;
typedef __attribute__((ext_vector_type(4))) float f32x4;
typedef __attribute__((ext_vector_type(16))) float f32x16;

__device__ __forceinline__ unsigned short f2b(float x) {
    uint32_t u = __float_as_uint(x);
    u += 0x7FFFu + ((u >> 16) & 1u);   // RNE
    return (unsigned short)(u >> 16);
}
__device__ __forceinline__ float b2f(unsigned short h) {
    return __uint_as_float(((uint32_t)h) << 16);
}

#define L_SEQ 512
#define N_AA 21
#define DDIM 128
#define NCOL 2688        // 21*128
#define NSEQ 512         // 256 + 256
#define TSTRIDE 448      // padded 441
#define KTOT 10752       // 512*21
#define KWORDS_TOT 336   // 10752/32
#define ZCH 24           // k-chunks
#define KCHUNK 448       // 10752/24
#define KWORDS 14        // 448/32

// ---------------- kernel 1: repack X int32 -> u8, combined [512][512] ----------------
__global__ __launch_bounds__(256) void repack_kernel(const int* X1, const int* X2, uint8_t* X8) {
    int e = blockIdx.x * 256 + threadIdx.x;   // 262144 total
    if (e < 131072) X8[e] = (uint8_t)X1[e];
    else            X8[e] = (uint8_t)X2[e - 131072];
}

// ---------------- kernel 1b: one-hot bitmask Abits[seq][word] ----------------
__global__ __launch_bounds__(256) void abits_kernel(const uint8_t* X8, uint32_t* Abits) {
    int e = blockIdx.x * 256 + threadIdx.x;   // 512*336 = 172032
    if (e >= NSEQ * KWORDS_TOT) return;
    int seq = e / KWORDS_TOT, w = e - seq * KWORDS_TOT;
    int k0 = w * 32;
    int l_lo = k0 / N_AA;
    int l_hi = (k0 + 31) / N_AA;
    if (l_hi > L_SEQ - 1) l_hi = L_SEQ - 1;
    uint32_t bits = 0;
    for (int l = l_lo; l <= l_hi; ++l) {
        int aa = X8[(size_t)seq * L_SEQ + l];
        int pos = l * N_AA + aa - k0;
        if (pos >= 0 && pos < 32) bits |= (1u << pos);
    }
    Abits[e] = bits;
}

// ---------------- kernel 2: w = sigmoid(wm) -> w32 + wswz (MFMA-frag order) --------
__global__ __launch_bounds__(256) void w_build_kernel(const float* wp, float* w32, unsigned short* wswz) {
    int e = blockIdx.x * 256 + threadIdx.x;   // 262144 = 512*512
    int p = e >> 9, q = e & 511;
    float x = 0.0f;
    if (p > q)      x = wp[p * (p - 1) / 2 + q];
    else if (p < q) x = wp[q * (q - 1) / 2 + p];
    float s = 1.0f / (1.0f + expf(-x));
    w32[e] = s;
    int nb = p >> 5, lr = p & 31;
    int kb = q >> 4, hf = (q >> 3) & 1, j = q & 7;
    wswz[(size_t)((nb * 32 + kb) * 512) + (hf * 32 + lr) * 8 + j] = f2b(s);
}

// ---------------- kernel 3a: E init with bias ----------------
__global__ __launch_bounds__(256) void e_init_kernel(const float* bvec, float* E) {
    int e = blockIdx.x * 256 + threadIdx.x;   // 512*2688 = 1376256
    int c = e % NCOL;
    E[e] = bvec[c];
}

// ---------------- kernel 3b: E += OneHot @ W via MFMA (hi-only bf16) ---------------
// grid (21 n-tiles of 128, 4 m-tiles of 128, 24 k-chunks of 448). 256 thr = 4 waves.
// Wave wid: mbase (wid&1)*64 (2 subtiles), nbase (wid>>1)*64 (2 subtiles) -> 64 acc.
__global__ __launch_bounds__(256) void e_mfma_kernel(const uint32_t* Abits, const float* W, float* E) {
    __shared__ uint32_t Ab[128 * 15];
    int t = threadIdx.x;
    int c0 = blockIdx.x * 128;
    int m0 = blockIdx.y * 128;
    int w0 = blockIdx.z * KWORDS;

    for (int idx = t; idx < 128 * KWORDS; idx += 256) {
        int r = idx / KWORDS, w = idx - r * KWORDS;
        Ab[r * 15 + w] = Abits[(size_t)(m0 + r) * KWORDS_TOT + w0 + w];
    }
    __syncthreads();

    int wid = t >> 6, lane = t & 63;
    int lr = lane & 31, hf = lane >> 5;
    int mbase = (wid & 1) * 64;
    int nbase = (wid >> 1) * 64;

    f32x16 acc[2][2];
#pragma unroll
    for (int s = 0; s < 2; ++s)
#pragma unroll
        for (int o = 0; o < 2; ++o)
#pragma unroll
            for (int r = 0; r < 16; ++r) acc[s][o][r] = 0.f;

    int kglob0 = blockIdx.z * KCHUNK;
    const float* Wp = W + (size_t)(kglob0 + hf * 8) * NCOL + c0 + nbase + lr;

    for (int ks = 0; ks < KCHUNK / 16; ++ks) {
        // A fragments (one-hot from bitmask)
        int word = ks >> 1;
        int b0 = (ks & 1) * 16 + hf * 8;
        bf16x8 afrag[2];
#pragma unroll
        for (int s = 0; s < 2; ++s) {
            uint32_t bits = Ab[(mbase + s * 32 + lr) * 15 + word];
            uint32_t bb = (bits >> b0) & 0xFFu;
            union { bf16x8 v; uint32_t u[4]; } af;
#pragma unroll
            for (int p = 0; p < 4; ++p) {
                uint32_t u = 0;
                if ((bb >> (2 * p)) & 1u)     u |= 0x3F80u;
                if ((bb >> (2 * p + 1)) & 1u) u |= 0x3F800000u;
                af.u[p] = u;
            }
            afrag[s] = af.v;
        }
        // B fragments: 2 n-subtiles, RNE bf16 (hi only)
#pragma unroll
        for (int o = 0; o < 2; ++o) {
            const float* wp_ = Wp + o * 32;
            float f[8];
#pragma unroll
            for (int j = 0; j < 8; ++j) f[j] = wp_[(size_t)j * NCOL];
            union { bf16x8 v; uint32_t u[4]; } bh;
#pragma unroll
            for (int p = 0; p < 4; ++p)
                bh.u[p] = (uint32_t)f2b(f[2 * p]) | ((uint32_t)f2b(f[2 * p + 1]) << 16);
#pragma unroll
            for (int s = 0; s < 2; ++s)
                acc[s][o] = __builtin_amdgcn_mfma_f32_32x32x16_bf16(afrag[s], bh.v, acc[s][o], 0, 0, 0);
        }
        Wp += (size_t)16 * NCOL;
    }

    // epilogue: atomic accumulate into E
#pragma unroll
    for (int s = 0; s < 2; ++s)
#pragma unroll
        for (int o = 0; o < 2; ++o)
#pragma unroll
            for (int r = 0; r < 16; ++r) {
                int row = (r & 3) + 8 * (r >> 2) + 4 * hf;
                float* dst = E + (size_t)(m0 + mbase + s * 32 + row) * NCOL + c0 + nbase + o * 32 + lr;
                atomicAdd(dst, acc[s][o][r]);
            }
}

// ---------------- kernel 4: T[n] = E[n] @ E[n]^T  (21x21), float4 LDS --------------
__global__ __launch_bounds__(256) void t_kernel(const float* E, float* T) {
    __shared__ float4 Es4[21 * 33];   // row stride 33 -> bank-conflict-free
    int t = threadIdx.x, n = blockIdx.x;
    for (int e = t; e < 21 * 32; e += 256) {
        int r = e >> 5, d = e & 31;
        Es4[r * 33 + d] = *(const float4*)(E + (size_t)n * NCOL + r * 128 + d * 4);
    }
    __syncthreads();
    for (int e = t; e < 441; e += 256) {
        int r = e / 21, c = e - r * 21;
        const float4* ar = &Es4[r * 33];
        const float4* br = &Es4[c * 33];
        float s = 0.f;
#pragma unroll 8
        for (int d = 0; d < 32; ++d) {
            float4 a = ar[d], b = br[d];
            s += a.x * b.x + a.y * b.y + a.z * b.z + a.w * b.w;
        }
        T[(size_t)n * TSTRIDE + e] = s;
    }
}

// ---------------- kernel 5: kinv, n-tile 2 (w32 row reuse) ----------------
__global__ __launch_bounds__(256) void k_kernel(const uint8_t* X8, const float* T, const float* w32, float* kinv) {
    __shared__ __align__(16) float dvec[2][512];
    __shared__ float Td[2][21];
    __shared__ float red[2][256];
    int t = threadIdx.x, n0 = blockIdx.x * 2;
    if (t < 42) Td[t / 21][t % 21] = T[(size_t)(n0 + t / 21) * TSTRIDE + (t % 21) * 22];
    __syncthreads();
    for (int e = t; e < 1024; e += 256) {
        int nn = e >> 9, l = e & 511;
        dvec[nn][l] = Td[nn][X8[(size_t)(n0 + nn) * 512 + l]];
    }
    __syncthreads();
    float p0 = 0.f, p1 = 0.f;
    for (int p = t; p < 512; p += 256) {
        const float4* wr4 = (const float4*)(w32 + (size_t)p * 512);
        const float4* d0 = (const float4*)dvec[0];
        const float4* d1 = (const float4*)dvec[1];
        float dot0 = 0.f, dot1 = 0.f;
        for (int q = 0; q < 128; ++q) {
            float4 wv = wr4[q];
            float4 a = d0[q], b = d1[q];
            dot0 += wv.x * a.x + wv.y * a.y + wv.z * a.z + wv.w * a.w;
            dot1 += wv.x * b.x + wv.y * b.y + wv.z * b.z + wv.w * b.w;
        }
        p0 += dvec[0][p] * dot0;
        p1 += dvec[1][p] * dot1;
    }
    red[0][t] = p0;
    red[1][t] = p1;
    __syncthreads();
    for (int s = 128; s > 0; s >>= 1) {
        if (t < s) { red[0][t] += red[0][t + s]; red[1][t] += red[1][t + s]; }
        __syncthreads();
    }
    if (t < 2) kinv[n0 + t] = 1.0f / sqrtf(red[t][0]);
}

// ---------------- kernel 6: main pair GEMM (32x32x16 MFMA, swizzled B) -------------
__global__ __launch_bounds__(256) void k4_kernel(const uint8_t* X8, const float* T,
                                                 const unsigned short* wswz, const float* kinv,
                                                 const float* Ainp, float* out) {
    __shared__ unsigned short Sh[32 * 520];
    __shared__ unsigned short Ts1h[4 * 441];   // bf16 of 0.5*T1
    __shared__ unsigned short Ts2h[8 * 441];   // bf16 of 0.5*T2
    __shared__ unsigned short A21[4 * 512];    // X1 row values * 21
    __shared__ uint8_t Xs2[8 * 512];
    __shared__ float Kacc[4][32];

    int t = threadIdx.x;
    int i0 = blockIdx.x * 4;
    int j0 = blockIdx.y * 8;

    for (int e = t; e < 4 * 512; e += 256)
        A21[e] = (unsigned short)(21 * X8[(size_t)(i0 + (e >> 9)) * 512 + (e & 511)]);
    {
        const uint32_t* s2 = (const uint32_t*)(X8 + (size_t)(256 + j0) * 512);
        uint32_t* d2 = (uint32_t*)Xs2;
        for (int e = t; e < 1024; e += 256) d2[e] = s2[e];
    }
    for (int e = t; e < 4 * 441; e += 256) {
        int r = e / 441, c = e - r * 441;
        Ts1h[e] = f2b(0.5f * T[(size_t)(i0 + r) * TSTRIDE + c]);
    }
    for (int e = t; e < 8 * 441; e += 256) {
        int r = e / 441, c = e - r * 441;
        Ts2h[e] = f2b(0.5f * T[(size_t)(256 + j0 + r) * TSTRIDE + c]);
    }
    __syncthreads();

    // build S tile: 2 elems per thread-iter, packed u32 write
    for (int e2 = t; e2 < 32 * 256; e2 += 256) {
        int pr = e2 >> 8, p = (e2 & 255) * 2;
        int ti = pr >> 3, tj = pr & 7;
        uint32_t a2 = *(const uint32_t*)&A21[ti * 512 + p];          // two u16 a*21
        uint32_t b2 = *(const unsigned short*)&Xs2[tj * 512 + p];    // two u8 b
        int i1a = (a2 & 0xFFFFu) + (b2 & 0xFFu);
        int i1b = (a2 >> 16)     + ((b2 >> 8) & 0xFFu);
        float v0 = b2f(Ts1h[ti * 441 + i1a]) + b2f(Ts2h[tj * 441 + i1a]);
        float v1 = b2f(Ts1h[ti * 441 + i1b]) + b2f(Ts2h[tj * 441 + i1b]);
        *(uint32_t*)&Sh[pr * 520 + p] = (uint32_t)f2b(v0) | ((uint32_t)f2b(v1) << 16);
    }
    __syncthreads();

    int wid = t >> 6, lane = t & 63;
    int lr = lane & 31, hf = lane >> 5;
    int n_base = wid * 128;

    const unsigned short* Sa = &Sh[lr * 520 + hf * 8];
    const unsigned short* Bz0 = wswz + (size_t)((wid * 4 + 0) * 32) * 512 + lane * 8;
    const unsigned short* Bz1 = wswz + (size_t)((wid * 4 + 1) * 32) * 512 + lane * 8;
    const unsigned short* Bz2 = wswz + (size_t)((wid * 4 + 2) * 32) * 512 + lane * 8;
    const unsigned short* Bz3 = wswz + (size_t)((wid * 4 + 3) * 32) * 512 + lane * 8;

    f32x16 acc0, acc1, acc2, acc3;
#pragma unroll
    for (int j = 0; j < 16; ++j) { acc0[j] = 0.f; acc1[j] = 0.f; acc2[j] = 0.f; acc3[j] = 0.f; }

#pragma unroll 2
    for (int kt = 0; kt < 32; ++kt) {
        bf16x8 av = *(const bf16x8*)(Sa + kt * 16);
        bf16x8 bv0 = *(const bf16x8*)(Bz0 + kt * 512);
        bf16x8 bv1 = *(const bf16x8*)(Bz1 + kt * 512);
        bf16x8 bv2 = *(const bf16x8*)(Bz2 + kt * 512);
        bf16x8 bv3 = *(const bf16x8*)(Bz3 + kt * 512);
        acc0 = __builtin_amdgcn_mfma_f32_32x32x16_bf16(av, bv0, acc0, 0, 0, 0);
        acc1 = __builtin_amdgcn_mfma_f32_32x32x16_bf16(av, bv1, acc1, 0, 0, 0);
        acc2 = __builtin_amdgcn_mfma_f32_32x32x16_bf16(av, bv2, acc2, 0, 0, 0);
        acc3 = __builtin_amdgcn_mfma_f32_32x32x16_bf16(av, bv3, acc3, 0, 0, 0);
    }

    float prow[16];
#pragma unroll
    for (int r = 0; r < 16; ++r) prow[r] = 0.f;
#pragma unroll
    for (int r = 0; r < 16; ++r) {
        int row = (r & 3) + 8 * (r >> 2) + 4 * hf;
        prow[r] += acc0[r] * b2f(Sh[row * 520 + (n_base +  0 + lr)]);
        prow[r] += acc1[r] * b2f(Sh[row * 520 + (n_base + 32 + lr)]);
        prow[r] += acc2[r] * b2f(Sh[row * 520 + (n_base + 64 + lr)]);
        prow[r] += acc3[r] * b2f(Sh[row * 520 + (n_base + 96 + lr)]);
    }
#pragma unroll
    for (int r = 0; r < 16; ++r) {
        float v = prow[r];
        v += __shfl_xor(v, 1);
        v += __shfl_xor(v, 2);
        v += __shfl_xor(v, 4);
        v += __shfl_xor(v, 8);
        v += __shfl_xor(v, 16);
        if (lr == 0) {
            int row = (r & 3) + 8 * (r >> 2) + 4 * hf;
            Kacc[wid][row] = v;
        }
    }
    __syncthreads();

    if (t < 32) {
        float K = Kacc[0][t] + Kacc[1][t] + Kacc[2][t] + Kacc[3][t];
        int ti = t >> 3, tj = t & 7;
        int i = i0 + ti, j = j0 + tj;
        float a0 = Ainp[0];
        out[i * 256 + j] = a0 * a0 * K * kinv[i] * kinv[256 + j];
    }
}

// ---------------- launcher ----------------
extern "C" void kernel_launch(void* const* d_in, const int* in_sizes, int n_in,
                              void* d_out, int out_size, void* d_ws, size_t ws_size,
                              hipStream_t stream) {
    const int*   X1 = (const int*)d_in[0];
    const int*   X2 = (const int*)d_in[1];
    const float* W  = (const float*)d_in[2];
    const float* b  = (const float*)d_in[3];
    const float* wp = (const float*)d_in[4];
    const float* a  = (const float*)d_in[5];
    float* out = (float*)d_out;

    char* ws = (char*)d_ws;
    float*          E     = (float*)(ws + 0);                 // 5,505,024
    float*          T     = (float*)(ws + 5505024);           //   917,504
    float*          w32   = (float*)(ws + 6422528);           // 1,048,576
    unsigned short* wswz  = (unsigned short*)(ws + 7471104);  //   524,288
    float*          kinv  = (float*)(ws + 7995392);           //     2,048
    uint8_t*        X8    = (uint8_t*)(ws + 7997440);         //   262,144
    uint32_t*       Abits = (uint32_t*)(ws + 8259584);        //   688,128  (end 8,947,712)

    repack_kernel<<<1024, 256, 0, stream>>>(X1, X2, X8);
    abits_kernel<<<672, 256, 0, stream>>>(X8, Abits);
    w_build_kernel<<<1024, 256, 0, stream>>>(wp, w32, wswz);
    e_init_kernel<<<5376, 256, 0, stream>>>(b, E);
    e_mfma_kernel<<<dim3(21, 4, ZCH), 256, 0, stream>>>(Abits, W, E);
    t_kernel<<<512, 256, 0, stream>>>(E, T);
    k_kernel<<<256, 256, 0, stream>>>(X8, T, w32, kinv);
    k4_kernel<<<dim3(64, 32), 256, 0, stream>>>(X8, T, wswz, kinv, a, out);
}

// Round 5
// 406.510 us; speedup vs baseline: 1.1449x; 1.1449x over previous
//
#include <hip/hip_runtime.h>
#include <cstdint>
#include <cstddef>

// ---------------- types / helpers ----------------
typedef __attribute__((ext_vector_type(8))) __bf16 bf16x8;
typedef __attribute__((ext_vector_type(4))) float f32x4;
typedef __attribute__((ext_vector_type(16))) float f32x16;

__device__ __forceinline__ unsigned short f2b(float x) {
    uint32_t u = __float_as_uint(x);
    u += 0x7FFFu + ((u >> 16) & 1u);   // RNE
    return (unsigned short)(u >> 16);
}
__device__ __forceinline__ float b2f(unsigned short h) {
    return __uint_as_float(((uint32_t)h) << 16);
}

#define L_SEQ 512
#define N_AA 21
#define DDIM 128
#define NCOL 2688        // 21*128
#define NSEQ 512         // 256 + 256
#define TSTRIDE 448      // padded 441
#define KTOT 10752       // 512*21
#define KWORDS_TOT 336   // 10752/32
#define ZCH 12           // k-chunks
#define KCHUNK 896       // 10752/12
#define KWORDS 28        // 896/32
#define KBTOT 672        // 10752/16 k-subtiles

// ---------------- kernel 1: repack X int32 -> u8, combined [512][512] ----------------
__global__ __launch_bounds__(256) void repack_kernel(const int* X1, const int* X2, uint8_t* X8) {
    int e = blockIdx.x * 256 + threadIdx.x;   // 262144 total
    if (e < 131072) X8[e] = (uint8_t)X1[e];
    else            X8[e] = (uint8_t)X2[e - 131072];
}

// ---------------- kernel 1b: one-hot bitmask Abits[seq][word] ----------------
__global__ __launch_bounds__(256) void abits_kernel(const uint8_t* X8, uint32_t* Abits) {
    int e = blockIdx.x * 256 + threadIdx.x;   // 512*336 = 172032
    if (e >= NSEQ * KWORDS_TOT) return;
    int seq = e / KWORDS_TOT, w = e - seq * KWORDS_TOT;
    int k0 = w * 32;
    int l_lo = k0 / N_AA;
    int l_hi = (k0 + 31) / N_AA;
    if (l_hi > L_SEQ - 1) l_hi = L_SEQ - 1;
    uint32_t bits = 0;
    for (int l = l_lo; l <= l_hi; ++l) {
        int aa = X8[(size_t)seq * L_SEQ + l];
        int pos = l * N_AA + aa - k0;
        if (pos >= 0 && pos < 32) bits |= (1u << pos);
    }
    Abits[e] = bits;
}

// ---------------- kernel 2: w = sigmoid(wm) -> w32 + wswz (MFMA-frag order) --------
__global__ __launch_bounds__(256) void w_build_kernel(const float* wp, float* w32, unsigned short* wswz) {
    int e = blockIdx.x * 256 + threadIdx.x;   // 262144 = 512*512
    int p = e >> 9, q = e & 511;
    float x = 0.0f;
    if (p > q)      x = wp[p * (p - 1) / 2 + q];
    else if (p < q) x = wp[q * (q - 1) / 2 + p];
    float s = 1.0f / (1.0f + expf(-x));
    w32[e] = s;
    int nb = p >> 5, lr = p & 31;
    int kb = q >> 4, hf = (q >> 3) & 1, j = q & 7;
    wswz[(size_t)((nb * 32 + kb) * 512) + (hf * 32 + lr) * 8 + j] = f2b(s);
}

// ---------------- kernel 3a: E init with bias ----------------
__global__ __launch_bounds__(256) void e_init_kernel(const float* bvec, float* E) {
    int e = blockIdx.x * 256 + threadIdx.x;   // 512*2688 = 1376256
    int c = e % NCOL;
    E[e] = bvec[c];
}

// ---------------- kernel 3b-pre: W fp32 row-major -> Wbz bf16 fragment-swizzled ----
// Fragment tile (cb: 32 cols, kb: 16 ks): element (k=kb*16+hf*8+j, c=cb*32+lr) stored
// at Wbz[(cb*672 + kb)*512 + (hf*32+lr)*8 + j]. Block: 16 k x 384 c, LDS transpose.
__global__ __launch_bounds__(256) void wbz_kernel(const float* W, unsigned short* Wbz) {
    __shared__ unsigned short Wt[384 * 24];   // [c_local][k], stride 24 (16B-aligned rows)
    int t = threadIdx.x;
    int k0 = blockIdx.x * 16;
    int c0 = blockIdx.y * 384;
    // stage + convert: 16x384 floats, coalesced float4 reads
    for (int it = 0; it < 6; ++it) {
        int flat = t + it * 256;            // 0..1535 float4's
        int k = flat / 96, cq = flat - k * 96;
        int cl = cq * 4;
        float4 g = *(const float4*)(W + (size_t)(k0 + k) * NCOL + c0 + cl);
        Wt[(cl + 0) * 24 + k] = f2b(g.x);
        Wt[(cl + 1) * 24 + k] = f2b(g.y);
        Wt[(cl + 2) * 24 + k] = f2b(g.z);
        Wt[(cl + 3) * 24 + k] = f2b(g.w);
    }
    __syncthreads();
    // write fragments: 12 cb-subtiles x 64 lanes x 16B
    int lane_o = t & 63, lr = lane_o & 31, hf = lane_o >> 5;
    int cb0 = t >> 6;
    int kb = k0 >> 4;
    for (int it = 0; it < 3; ++it) {
        int cbl = cb0 + it * 4;             // 0..11
        int cl = cbl * 32 + lr;
        uint4 v = *(const uint4*)&Wt[cl * 24 + hf * 8];
        int cb_g = (c0 >> 5) + cbl;
        *(uint4*)&Wbz[(size_t)(cb_g * KBTOT + kb) * 512 + lane_o * 8] = v;
    }
}

// ---------------- kernel 3b (fast): E += OneHot @ Wbz via MFMA, b128 B loads -------
// grid (21 c-tiles of 128, 2 m-tiles of 256, 12 k-chunks of 896). 256 thr = 4 waves.
// Wave wid: mbase (wid&1)*128 (4 subtiles), nbase (wid>>1)*64 (2 subtiles).
__global__ __launch_bounds__(256) void e_mfma_bz_kernel(const uint32_t* Abits, const unsigned short* Wbz, float* E) {
    __shared__ uint32_t Ab[256 * 29];
    int t = threadIdx.x;
    int c0 = blockIdx.x * 128;
    int m0 = blockIdx.y * 256;
    int w0 = blockIdx.z * KWORDS;

    for (int idx = t; idx < 256 * KWORDS; idx += 256) {
        int r = idx / KWORDS, w = idx - r * KWORDS;
        Ab[r * 29 + w] = Abits[(size_t)(m0 + r) * KWORDS_TOT + w0 + w];
    }
    __syncthreads();

    int wid = t >> 6, lane = t & 63;
    int lr = lane & 31, hf = lane >> 5;
    int mbase = (wid & 1) * 128;
    int nbase = (wid >> 1) * 64;

    f32x16 acc[4][2];
#pragma unroll
    for (int s = 0; s < 4; ++s)
#pragma unroll
        for (int o = 0; o < 2; ++o)
#pragma unroll
            for (int r = 0; r < 16; ++r) acc[s][o][r] = 0.f;

    int kb0 = blockIdx.z * (KCHUNK / 16);
    const unsigned short* Bz0 = Wbz + (size_t)(((c0 >> 5) + (wid >> 1) * 2 + 0) * KBTOT + kb0) * 512 + lane * 8;
    const unsigned short* Bz1 = Wbz + (size_t)(((c0 >> 5) + (wid >> 1) * 2 + 1) * KBTOT + kb0) * 512 + lane * 8;

#pragma unroll 2
    for (int ks = 0; ks < KCHUNK / 16; ++ks) {
        int word = ks >> 1;
        int b0 = (ks & 1) * 16 + hf * 8;
        bf16x8 afrag[4];
#pragma unroll
        for (int s = 0; s < 4; ++s) {
            uint32_t bits = Ab[(mbase + s * 32 + lr) * 29 + word];
            uint32_t bb = (bits >> b0) & 0xFFu;
            union { bf16x8 v; uint32_t u[4]; } af;
#pragma unroll
            for (int p = 0; p < 4; ++p) {
                uint32_t u = 0;
                if ((bb >> (2 * p)) & 1u)     u |= 0x3F80u;
                if ((bb >> (2 * p + 1)) & 1u) u |= 0x3F800000u;
                af.u[p] = u;
            }
            afrag[s] = af.v;
        }
        bf16x8 bv0 = *(const bf16x8*)(Bz0 + ks * 512);
        bf16x8 bv1 = *(const bf16x8*)(Bz1 + ks * 512);
#pragma unroll
        for (int s = 0; s < 4; ++s) {
            acc[s][0] = __builtin_amdgcn_mfma_f32_32x32x16_bf16(afrag[s], bv0, acc[s][0], 0, 0, 0);
            acc[s][1] = __builtin_amdgcn_mfma_f32_32x32x16_bf16(afrag[s], bv1, acc[s][1], 0, 0, 0);
        }
    }

#pragma unroll
    for (int s = 0; s < 4; ++s)
#pragma unroll
        for (int o = 0; o < 2; ++o)
#pragma unroll
            for (int r = 0; r < 16; ++r) {
                int row = (r & 3) + 8 * (r >> 2) + 4 * hf;
                float* dst = E + (size_t)(m0 + mbase + s * 32 + row) * NCOL + c0 + nbase + o * 32 + lr;
                atomicAdd(dst, acc[s][o][r]);
            }
}

// ---------------- kernel 3b (fallback, R3-proven): direct fp32 B loads -------------
__global__ __launch_bounds__(256) void e_mfma_f32_kernel(const uint32_t* Abits, const float* W, float* E) {
    __shared__ uint32_t Ab[256 * 29];
    int t = threadIdx.x;
    int c0 = blockIdx.x * 128;
    int m0 = blockIdx.y * 256;
    int w0 = blockIdx.z * KWORDS;

    for (int idx = t; idx < 256 * KWORDS; idx += 256) {
        int r = idx / KWORDS, w = idx - r * KWORDS;
        Ab[r * 29 + w] = Abits[(size_t)(m0 + r) * KWORDS_TOT + w0 + w];
    }
    __syncthreads();

    int wid = t >> 6, lane = t & 63;
    int lr = lane & 31, hf = lane >> 5;
    int mbase = (wid & 1) * 128;
    int nbase = (wid >> 1) * 64;

    f32x16 acc[4][2];
#pragma unroll
    for (int s = 0; s < 4; ++s)
#pragma unroll
        for (int o = 0; o < 2; ++o)
#pragma unroll
            for (int r = 0; r < 16; ++r) acc[s][o][r] = 0.f;

    int kglob0 = blockIdx.z * KCHUNK;
    const float* Wp = W + (size_t)(kglob0 + hf * 8) * NCOL + c0 + nbase + lr;

    for (int ks = 0; ks < KCHUNK / 16; ++ks) {
        int word = ks >> 1;
        int b0 = (ks & 1) * 16 + hf * 8;
        bf16x8 afrag[4];
#pragma unroll
        for (int s = 0; s < 4; ++s) {
            uint32_t bits = Ab[(mbase + s * 32 + lr) * 29 + word];
            uint32_t bb = (bits >> b0) & 0xFFu;
            union { bf16x8 v; uint32_t u[4]; } af;
#pragma unroll
            for (int p = 0; p < 4; ++p) {
                uint32_t u = 0;
                if ((bb >> (2 * p)) & 1u)     u |= 0x3F80u;
                if ((bb >> (2 * p + 1)) & 1u) u |= 0x3F800000u;
                af.u[p] = u;
            }
            afrag[s] = af.v;
        }
#pragma unroll
        for (int o = 0; o < 2; ++o) {
            const float* wp_ = Wp + o * 32;
            float f[8];
#pragma unroll
            for (int j = 0; j < 8; ++j) f[j] = wp_[(size_t)j * NCOL];
            union { bf16x8 v; uint32_t u[4]; } bh;
#pragma unroll
            for (int p = 0; p < 4; ++p)
                bh.u[p] = (uint32_t)f2b(f[2 * p]) | ((uint32_t)f2b(f[2 * p + 1]) << 16);
#pragma unroll
            for (int s = 0; s < 4; ++s)
                acc[s][o] = __builtin_amdgcn_mfma_f32_32x32x16_bf16(afrag[s], bh.v, acc[s][o], 0, 0, 0);
        }
        Wp += (size_t)16 * NCOL;
    }

#pragma unroll
    for (int s = 0; s < 4; ++s)
#pragma unroll
        for (int o = 0; o < 2; ++o)
#pragma unroll
            for (int r = 0; r < 16; ++r) {
                int row = (r & 3) + 8 * (r >> 2) + 4 * hf;
                float* dst = E + (size_t)(m0 + mbase + s * 32 + row) * NCOL + c0 + nbase + o * 32 + lr;
                atomicAdd(dst, acc[s][o][r]);
            }
}

// ---------------- kernel 4: T[n] = E[n] @ E[n]^T  (21x21), float4 LDS --------------
__global__ __launch_bounds__(256) void t_kernel(const float* E, float* T) {
    __shared__ float4 Es4[21 * 33];
    int t = threadIdx.x, n = blockIdx.x;
    for (int e = t; e < 21 * 32; e += 256) {
        int r = e >> 5, d = e & 31;
        Es4[r * 33 + d] = *(const float4*)(E + (size_t)n * NCOL + r * 128 + d * 4);
    }
    __syncthreads();
    for (int e = t; e < 441; e += 256) {
        int r = e / 21, c = e - r * 21;
        const float4* ar = &Es4[r * 33];
        const float4* br = &Es4[c * 33];
        float s = 0.f;
#pragma unroll 8
        for (int d = 0; d < 32; ++d) {
            float4 a = ar[d], b = br[d];
            s += a.x * b.x + a.y * b.y + a.z * b.z + a.w * b.w;
        }
        T[(size_t)n * TSTRIDE + e] = s;
    }
}

// ---------------- kernel 5: kinv, n-tile 2 (w32 row reuse) ----------------
__global__ __launch_bounds__(256) void k_kernel(const uint8_t* X8, const float* T, const float* w32, float* kinv) {
    __shared__ __align__(16) float dvec[2][512];
    __shared__ float Td[2][21];
    __shared__ float red[2][256];
    int t = threadIdx.x, n0 = blockIdx.x * 2;
    if (t < 42) Td[t / 21][t % 21] = T[(size_t)(n0 + t / 21) * TSTRIDE + (t % 21) * 22];
    __syncthreads();
    for (int e = t; e < 1024; e += 256) {
        int nn = e >> 9, l = e & 511;
        dvec[nn][l] = Td[nn][X8[(size_t)(n0 + nn) * 512 + l]];
    }
    __syncthreads();
    float p0 = 0.f, p1 = 0.f;
    for (int p = t; p < 512; p += 256) {
        const float4* wr4 = (const float4*)(w32 + (size_t)p * 512);
        const float4* d0 = (const float4*)dvec[0];
        const float4* d1 = (const float4*)dvec[1];
        float dot0 = 0.f, dot1 = 0.f;
        for (int q = 0; q < 128; ++q) {
            float4 wv = wr4[q];
            float4 a = d0[q], b = d1[q];
            dot0 += wv.x * a.x + wv.y * a.y + wv.z * a.z + wv.w * a.w;
            dot1 += wv.x * b.x + wv.y * b.y + wv.z * b.z + wv.w * b.w;
        }
        p0 += dvec[0][p] * dot0;
        p1 += dvec[1][p] * dot1;
    }
    red[0][t] = p0;
    red[1][t] = p1;
    __syncthreads();
    for (int s = 128; s > 0; s >>= 1) {
        if (t < s) { red[0][t] += red[0][t + s]; red[1][t] += red[1][t + s]; }
        __syncthreads();
    }
    if (t < 2) kinv[n0 + t] = 1.0f / sqrtf(red[t][0]);
}

// ---------------- kernel 6: main pair GEMM (32x32x16 MFMA, swizzled B) -------------
__global__ __launch_bounds__(256) void k4_kernel(const uint8_t* X8, const float* T,
                                                 const unsigned short* wswz, const float* kinv,
                                                 const float* Ainp, float* out) {
    __shared__ unsigned short Sh[32 * 520];
    __shared__ unsigned short Ts1h[4 * 441];
    __shared__ unsigned short Ts2h[8 * 441];
    __shared__ unsigned short A21[4 * 512];
    __shared__ uint8_t Xs2[8 * 512];
    __shared__ float Kacc[4][32];

    int t = threadIdx.x;
    int i0 = blockIdx.x * 4;
    int j0 = blockIdx.y * 8;

    for (int e = t; e < 4 * 512; e += 256)
        A21[e] = (unsigned short)(21 * X8[(size_t)(i0 + (e >> 9)) * 512 + (e & 511)]);
    {
        const uint32_t* s2 = (const uint32_t*)(X8 + (size_t)(256 + j0) * 512);
        uint32_t* d2 = (uint32_t*)Xs2;
        for (int e = t; e < 1024; e += 256) d2[e] = s2[e];
    }
    for (int e = t; e < 4 * 441; e += 256) {
        int r = e / 441, c = e - r * 441;
        Ts1h[e] = f2b(0.5f * T[(size_t)(i0 + r) * TSTRIDE + c]);
    }
    for (int e = t; e < 8 * 441; e += 256) {
        int r = e / 441, c = e - r * 441;
        Ts2h[e] = f2b(0.5f * T[(size_t)(256 + j0 + r) * TSTRIDE + c]);
    }
    __syncthreads();

    for (int e2 = t; e2 < 32 * 256; e2 += 256) {
        int pr = e2 >> 8, p = (e2 & 255) * 2;
        int ti = pr >> 3, tj = pr & 7;
        uint32_t a2 = *(const uint32_t*)&A21[ti * 512 + p];
        uint32_t b2 = *(const unsigned short*)&Xs2[tj * 512 + p];
        int i1a = (a2 & 0xFFFFu) + (b2 & 0xFFu);
        int i1b = (a2 >> 16)     + ((b2 >> 8) & 0xFFu);
        float v0 = b2f(Ts1h[ti * 441 + i1a]) + b2f(Ts2h[tj * 441 + i1a]);
        float v1 = b2f(Ts1h[ti * 441 + i1b]) + b2f(Ts2h[tj * 441 + i1b]);
        *(uint32_t*)&Sh[pr * 520 + p] = (uint32_t)f2b(v0) | ((uint32_t)f2b(v1) << 16);
    }
    __syncthreads();

    int wid = t >> 6, lane = t & 63;
    int lr = lane & 31, hf = lane >> 5;
    int n_base = wid * 128;

    const unsigned short* Sa = &Sh[lr * 520 + hf * 8];
    const unsigned short* Bz0 = wswz + (size_t)((wid * 4 + 0) * 32) * 512 + lane * 8;
    const unsigned short* Bz1 = wswz + (size_t)((wid * 4 + 1) * 32) * 512 + lane * 8;
    const unsigned short* Bz2 = wswz + (size_t)((wid * 4 + 2) * 32) * 512 + lane * 8;
    const unsigned short* Bz3 = wswz + (size_t)((wid * 4 + 3) * 32) * 512 + lane * 8;

    f32x16 acc0, acc1, acc2, acc3;
#pragma unroll
    for (int j = 0; j < 16; ++j) { acc0[j] = 0.f; acc1[j] = 0.f; acc2[j] = 0.f; acc3[j] = 0.f; }

#pragma unroll 2
    for (int kt = 0; kt < 32; ++kt) {
        bf16x8 av = *(const bf16x8*)(Sa + kt * 16);
        bf16x8 bv0 = *(const bf16x8*)(Bz0 + kt * 512);
        bf16x8 bv1 = *(const bf16x8*)(Bz1 + kt * 512);
        bf16x8 bv2 = *(const bf16x8*)(Bz2 + kt * 512);
        bf16x8 bv3 = *(const bf16x8*)(Bz3 + kt * 512);
        acc0 = __builtin_amdgcn_mfma_f32_32x32x16_bf16(av, bv0, acc0, 0, 0, 0);
        acc1 = __builtin_amdgcn_mfma_f32_32x32x16_bf16(av, bv1, acc1, 0, 0, 0);
        acc2 = __builtin_amdgcn_mfma_f32_32x32x16_bf16(av, bv2, acc2, 0, 0, 0);
        acc3 = __builtin_amdgcn_mfma_f32_32x32x16_bf16(av, bv3, acc3, 0, 0, 0);
    }

    float prow[16];
#pragma unroll
    for (int r = 0; r < 16; ++r) prow[r] = 0.f;
#pragma unroll
    for (int r = 0; r < 16; ++r) {
        int row = (r & 3) + 8 * (r >> 2) + 4 * hf;
        prow[r] += acc0[r] * b2f(Sh[row * 520 + (n_base +  0 + lr)]);
        prow[r] += acc1[r] * b2f(Sh[row * 520 + (n_base + 32 + lr)]);
        prow[r] += acc2[r] * b2f(Sh[row * 520 + (n_base + 64 + lr)]);
        prow[r] += acc3[r] * b2f(Sh[row * 520 + (n_base + 96 + lr)]);
    }
#pragma unroll
    for (int r = 0; r < 16; ++r) {
        float v = prow[r];
        v += __shfl_xor(v, 1);
        v += __shfl_xor(v, 2);
        v += __shfl_xor(v, 4);
        v += __shfl_xor(v, 8);
        v += __shfl_xor(v, 16);
        if (lr == 0) {
            int row = (r & 3) + 8 * (r >> 2) + 4 * hf;
            Kacc[wid][row] = v;
        }
    }
    __syncthreads();

    if (t < 32) {
        float K = Kacc[0][t] + Kacc[1][t] + Kacc[2][t] + Kacc[3][t];
        int ti = t >> 3, tj = t & 7;
        int i = i0 + ti, j = j0 + tj;
        float a0 = Ainp[0];
        out[i * 256 + j] = a0 * a0 * K * kinv[i] * kinv[256 + j];
    }
}

// ---------------- launcher ----------------
extern "C" void kernel_launch(void* const* d_in, const int* in_sizes, int n_in,
                              void* d_out, int out_size, void* d_ws, size_t ws_size,
                              hipStream_t stream) {
    const int*   X1 = (const int*)d_in[0];
    const int*   X2 = (const int*)d_in[1];
    const float* W  = (const float*)d_in[2];
    const float* b  = (const float*)d_in[3];
    const float* wp = (const float*)d_in[4];
    const float* a  = (const float*)d_in[5];
    float* out = (float*)d_out;

    char* ws = (char*)d_ws;
    float*          E     = (float*)(ws + 0);                 // 5,505,024
    float*          T     = (float*)(ws + 5505024);           //   917,504
    float*          w32   = (float*)(ws + 6422528);           // 1,048,576
    unsigned short* wswz  = (unsigned short*)(ws + 7471104);  //   524,288
    float*          kinv  = (float*)(ws + 7995392);           //     2,048
    uint8_t*        X8    = (uint8_t*)(ws + 7997440);         //   262,144
    uint32_t*       Abits = (uint32_t*)(ws + 8259584);        //   688,128  (end 8,947,712)
    unsigned short* Wbz   = (unsigned short*)(ws + 8947712);  // 57,802,752 (end 66,750,464)

    const bool big_ws = (ws_size >= (size_t)66750464);

    repack_kernel<<<1024, 256, 0, stream>>>(X1, X2, X8);
    abits_kernel<<<672, 256, 0, stream>>>(X8, Abits);
    w_build_kernel<<<1024, 256, 0, stream>>>(wp, w32, wswz);
    e_init_kernel<<<5376, 256, 0, stream>>>(b, E);
    if (big_ws) {
        wbz_kernel<<<dim3(KBTOT, 7), 256, 0, stream>>>(W, Wbz);
        e_mfma_bz_kernel<<<dim3(21, 2, ZCH), 256, 0, stream>>>(Abits, Wbz, E);
    } else {
        e_mfma_f32_kernel<<<dim3(21, 2, ZCH), 256, 0, stream>>>(Abits, W, E);
    }
    t_kernel<<<512, 256, 0, stream>>>(E, T);
    k_kernel<<<256, 256, 0, stream>>>(X8, T, w32, kinv);
    k4_kernel<<<dim3(64, 32), 256, 0, stream>>>(X8, T, wswz, kinv, a, out);
}

// Round 6
// 397.117 us; speedup vs baseline: 1.1720x; 1.0237x over previous
//
#include <hip/hip_runtime.h>
#include <cstdint>
#include <cstddef>

// ---------------- types / helpers ----------------
typedef __attribute__((ext_vector_type(8))) __bf16 bf16x8;
typedef __attribute__((ext_vector_type(4))) float f32x4;
typedef __attribute__((ext_vector_type(16))) float f32x16;

__device__ __forceinline__ unsigned short f2b(float x) {
    uint32_t u = __float_as_uint(x);
    u += 0x7FFFu + ((u >> 16) & 1u);   // RNE
    return (unsigned short)(u >> 16);
}
__device__ __forceinline__ float b2f(unsigned short h) {
    return __uint_as_float(((uint32_t)h) << 16);
}

#define L_SEQ 512
#define N_AA 21
#define DDIM 128
#define NCOL 2688        // 21*128
#define NSEQ 512         // 256 + 256
#define TSTRIDE 448      // padded 441
#define KTOT 10752       // 512*21
#define KWORDS_TOT 336   // 10752/32
#define ZCH 12           // k-chunks
#define KCHUNK 896       // 10752/12
#define KWORDS 28        // 896/32
#define KBTOT 672        // 10752/16 k-subtiles
#define NFRAG 56448      // 84 cb * 672 kb

// block-range sizes inside prep_kernel
#define PB_WBZ   14112   // 56448/4 fragments
#define PB_EINIT 5376
#define PB_REPACK 1024
#define PB_WBUILD 1024
#define PB_ABITS 672
#define PB_TOTAL (PB_WBZ + PB_EINIT + PB_REPACK + PB_WBUILD + PB_ABITS)

// ---------------- kernel 1: fused prologue ----------------
// Independent sub-jobs, dispatched by blockIdx range:
//   [0, 14112)          : W fp32 -> Wbz bf16 fragment-swizzled (no LDS, coalesced)
//   [14112, +5376)      : E init with bias
//   [+1024)             : X1/X2 int32 -> X8 u8
//   [+1024)             : w32 = sigmoid(wm), wswz = bf16 MFMA-frag order
//   [+672)              : one-hot bitmask Abits (reads X1/X2 directly)
__global__ __launch_bounds__(256) void prep_kernel(const int* X1, const int* X2,
                                                   const float* W, const float* bvec, const float* wp,
                                                   uint8_t* X8, uint32_t* Abits,
                                                   float* w32, unsigned short* wswz,
                                                   float* E, unsigned short* Wbz) {
    int bid = blockIdx.x;
    int t = threadIdx.x;
    if (bid < PB_WBZ) {
        // Wbz fragment (cb,kb): lane (hf,lr) holds W[kb*16+hf*8+j][cb*32+lr], j=0..7
        int f = bid * 4 + (t >> 6);
        int lane = t & 63, lr = lane & 31, hf = lane >> 5;
        int cb = f / KBTOT, kb = f - cb * KBTOT;
        const float* src = W + (size_t)(kb * 16 + hf * 8) * NCOL + cb * 32 + lr;
        union { uint4 q; unsigned short s[8]; } o;
#pragma unroll
        for (int j = 0; j < 8; ++j) o.s[j] = f2b(src[(size_t)j * NCOL]);
        *(uint4*)&Wbz[(size_t)f * 512 + lane * 8] = o.q;
        return;
    }
    bid -= PB_WBZ;
    if (bid < PB_EINIT) {
        int e = bid * 256 + t;             // 1,376,256
        E[e] = bvec[e % NCOL];
        return;
    }
    bid -= PB_EINIT;
    if (bid < PB_REPACK) {
        int e = bid * 256 + t;             // 262,144
        if (e < 131072) X8[e] = (uint8_t)X1[e];
        else            X8[e] = (uint8_t)X2[e - 131072];
        return;
    }
    bid -= PB_REPACK;
    if (bid < PB_WBUILD) {
        int e = bid * 256 + t;             // 262,144 = 512*512
        int p = e >> 9, q = e & 511;
        float x = 0.0f;
        if (p > q)      x = wp[p * (p - 1) / 2 + q];
        else if (p < q) x = wp[q * (q - 1) / 2 + p];
        float s = 1.0f / (1.0f + expf(-x));
        w32[e] = s;
        int nb = p >> 5, lr = p & 31;
        int kb = q >> 4, hf = (q >> 3) & 1, j = q & 7;
        wswz[(size_t)((nb * 32 + kb) * 512) + (hf * 32 + lr) * 8 + j] = f2b(s);
        return;
    }
    bid -= PB_WBUILD;
    {
        int e = bid * 256 + t;             // 172,032 = 512*336
        if (e >= NSEQ * KWORDS_TOT) return;
        int seq = e / KWORDS_TOT, w = e - seq * KWORDS_TOT;
        int k0 = w * 32;
        int l_lo = k0 / N_AA;
        int l_hi = (k0 + 31) / N_AA;
        if (l_hi > L_SEQ - 1) l_hi = L_SEQ - 1;
        uint32_t bits = 0;
        for (int l = l_lo; l <= l_hi; ++l) {
            int aa = (seq < 256) ? X1[(size_t)seq * L_SEQ + l]
                                 : X2[(size_t)(seq - 256) * L_SEQ + l];
            int pos = l * N_AA + aa - k0;
            if (pos >= 0 && pos < 32) bits |= (1u << pos);
        }
        Abits[e] = bits;
    }
}

// ---------------- kernel 2: E += OneHot @ Wbz via MFMA, b128 B loads ---------------
// grid (21 c-tiles of 128, 2 m-tiles of 256, 12 k-chunks of 896). 256 thr = 4 waves.
__global__ __launch_bounds__(256) void e_mfma_bz_kernel(const uint32_t* Abits, const unsigned short* Wbz, float* E) {
    __shared__ uint32_t Ab[256 * 29];
    int t = threadIdx.x;
    int c0 = blockIdx.x * 128;
    int m0 = blockIdx.y * 256;
    int w0 = blockIdx.z * KWORDS;

    for (int idx = t; idx < 256 * KWORDS; idx += 256) {
        int r = idx / KWORDS, w = idx - r * KWORDS;
        Ab[r * 29 + w] = Abits[(size_t)(m0 + r) * KWORDS_TOT + w0 + w];
    }
    __syncthreads();

    int wid = t >> 6, lane = t & 63;
    int lr = lane & 31, hf = lane >> 5;
    int mbase = (wid & 1) * 128;
    int nbase = (wid >> 1) * 64;

    f32x16 acc[4][2];
#pragma unroll
    for (int s = 0; s < 4; ++s)
#pragma unroll
        for (int o = 0; o < 2; ++o)
#pragma unroll
            for (int r = 0; r < 16; ++r) acc[s][o][r] = 0.f;

    int kb0 = blockIdx.z * (KCHUNK / 16);
    const unsigned short* Bz0 = Wbz + (size_t)(((c0 >> 5) + (wid >> 1) * 2 + 0) * KBTOT + kb0) * 512 + lane * 8;
    const unsigned short* Bz1 = Wbz + (size_t)(((c0 >> 5) + (wid >> 1) * 2 + 1) * KBTOT + kb0) * 512 + lane * 8;

#pragma unroll 2
    for (int ks = 0; ks < KCHUNK / 16; ++ks) {
        int word = ks >> 1;
        int b0 = (ks & 1) * 16 + hf * 8;
        bf16x8 afrag[4];
#pragma unroll
        for (int s = 0; s < 4; ++s) {
            uint32_t bits = Ab[(mbase + s * 32 + lr) * 29 + word];
            uint32_t bb = (bits >> b0) & 0xFFu;
            union { bf16x8 v; uint32_t u[4]; } af;
#pragma unroll
            for (int p = 0; p < 4; ++p) {
                uint32_t u = 0;
                if ((bb >> (2 * p)) & 1u)     u |= 0x3F80u;
                if ((bb >> (2 * p + 1)) & 1u) u |= 0x3F800000u;
                af.u[p] = u;
            }
            afrag[s] = af.v;
        }
        bf16x8 bv0 = *(const bf16x8*)(Bz0 + ks * 512);
        bf16x8 bv1 = *(const bf16x8*)(Bz1 + ks * 512);
#pragma unroll
        for (int s = 0; s < 4; ++s) {
            acc[s][0] = __builtin_amdgcn_mfma_f32_32x32x16_bf16(afrag[s], bv0, acc[s][0], 0, 0, 0);
            acc[s][1] = __builtin_amdgcn_mfma_f32_32x32x16_bf16(afrag[s], bv1, acc[s][1], 0, 0, 0);
        }
    }

#pragma unroll
    for (int s = 0; s < 4; ++s)
#pragma unroll
        for (int o = 0; o < 2; ++o)
#pragma unroll
            for (int r = 0; r < 16; ++r) {
                int row = (r & 3) + 8 * (r >> 2) + 4 * hf;
                float* dst = E + (size_t)(m0 + mbase + s * 32 + row) * NCOL + c0 + nbase + o * 32 + lr;
                atomicAdd(dst, acc[s][o][r]);
            }
}

// ---------------- kernel 3: T[n] = E[n] @ E[n]^T  (21x21), float4 LDS --------------
__global__ __launch_bounds__(256) void t_kernel(const float* E, float* T) {
    __shared__ float4 Es4[21 * 33];
    int t = threadIdx.x, n = blockIdx.x;
    for (int e = t; e < 21 * 32; e += 256) {
        int r = e >> 5, d = e & 31;
        Es4[r * 33 + d] = *(const float4*)(E + (size_t)n * NCOL + r * 128 + d * 4);
    }
    __syncthreads();
    for (int e = t; e < 441; e += 256) {
        int r = e / 21, c = e - r * 21;
        const float4* ar = &Es4[r * 33];
        const float4* br = &Es4[c * 33];
        float s = 0.f;
#pragma unroll 8
        for (int d = 0; d < 32; ++d) {
            float4 a = ar[d], b = br[d];
            s += a.x * b.x + a.y * b.y + a.z * b.z + a.w * b.w;
        }
        T[(size_t)n * TSTRIDE + e] = s;
    }
}

// ---------------- kernel 4: kinv, n-tile 4 (w32 row reuse) ----------------
__global__ __launch_bounds__(256) void k_kernel(const uint8_t* X8, const float* T, const float* w32, float* kinv) {
    __shared__ __align__(16) float dvec[4][512];
    __shared__ float Td[4][21];
    __shared__ float red[4][256];
    int t = threadIdx.x, n0 = blockIdx.x * 4;
    if (t < 84) Td[t / 21][t % 21] = T[(size_t)(n0 + t / 21) * TSTRIDE + (t % 21) * 22];
    __syncthreads();
    for (int e = t; e < 2048; e += 256) {
        int nn = e >> 9, l = e & 511;
        dvec[nn][l] = Td[nn][X8[(size_t)(n0 + nn) * 512 + l]];
    }
    __syncthreads();
    float p0 = 0.f, p1 = 0.f, p2 = 0.f, p3 = 0.f;
    for (int p = t; p < 512; p += 256) {
        const float4* wr4 = (const float4*)(w32 + (size_t)p * 512);
        float d0 = 0.f, d1 = 0.f, d2 = 0.f, d3 = 0.f;
        for (int q = 0; q < 128; ++q) {
            float4 wv = wr4[q];
            float4 a = ((const float4*)dvec[0])[q];
            float4 b = ((const float4*)dvec[1])[q];
            float4 c = ((const float4*)dvec[2])[q];
            float4 d = ((const float4*)dvec[3])[q];
            d0 += wv.x * a.x + wv.y * a.y + wv.z * a.z + wv.w * a.w;
            d1 += wv.x * b.x + wv.y * b.y + wv.z * b.z + wv.w * b.w;
            d2 += wv.x * c.x + wv.y * c.y + wv.z * c.z + wv.w * c.w;
            d3 += wv.x * d.x + wv.y * d.y + wv.z * d.z + wv.w * d.w;
        }
        p0 += dvec[0][p] * d0;
        p1 += dvec[1][p] * d1;
        p2 += dvec[2][p] * d2;
        p3 += dvec[3][p] * d3;
    }
    red[0][t] = p0; red[1][t] = p1; red[2][t] = p2; red[3][t] = p3;
    __syncthreads();
    for (int s = 128; s > 0; s >>= 1) {
        if (t < s) {
            red[0][t] += red[0][t + s];
            red[1][t] += red[1][t + s];
            red[2][t] += red[2][t + s];
            red[3][t] += red[3][t + s];
        }
        __syncthreads();
    }
    if (t < 4) kinv[n0 + t] = 1.0f / sqrtf(red[t][0]);
}

// ---------------- kernel 5: main pair GEMM (32x32x16 MFMA, swizzled B) -------------
__global__ __launch_bounds__(256) void k4_kernel(const uint8_t* X8, const float* T,
                                                 const unsigned short* wswz, const float* kinv,
                                                 const float* Ainp, float* out) {
    __shared__ unsigned short Sh[32 * 520];
    __shared__ unsigned short Ts1h[4 * 441];
    __shared__ unsigned short Ts2h[8 * 441];
    __shared__ unsigned short A21[4 * 512];
    __shared__ uint8_t Xs2[8 * 512];
    __shared__ float Kacc[4][32];

    int t = threadIdx.x;
    int i0 = blockIdx.x * 4;
    int j0 = blockIdx.y * 8;

    for (int e = t; e < 4 * 512; e += 256)
        A21[e] = (unsigned short)(21 * X8[(size_t)(i0 + (e >> 9)) * 512 + (e & 511)]);
    {
        const uint32_t* s2 = (const uint32_t*)(X8 + (size_t)(256 + j0) * 512);
        uint32_t* d2 = (uint32_t*)Xs2;
        for (int e = t; e < 1024; e += 256) d2[e] = s2[e];
    }
    for (int e = t; e < 4 * 441; e += 256) {
        int r = e / 441, c = e - r * 441;
        Ts1h[e] = f2b(0.5f * T[(size_t)(i0 + r) * TSTRIDE + c]);
    }
    for (int e = t; e < 8 * 441; e += 256) {
        int r = e / 441, c = e - r * 441;
        Ts2h[e] = f2b(0.5f * T[(size_t)(256 + j0 + r) * TSTRIDE + c]);
    }
    __syncthreads();

    // build S tile: 4 elems per thread-iter, packed u64 write
    for (int e4 = t; e4 < 32 * 128; e4 += 256) {
        int pr = e4 >> 7, p = (e4 & 127) * 4;
        int ti = pr >> 3, tj = pr & 7;
        uint64_t a4 = *(const uint64_t*)&A21[ti * 512 + p];   // 4 u16 (a*21)
        uint32_t b4 = *(const uint32_t*)&Xs2[tj * 512 + p];   // 4 u8
        const unsigned short* T1 = &Ts1h[ti * 441];
        const unsigned short* T2 = &Ts2h[tj * 441];
        uint64_t outw = 0;
#pragma unroll
        for (int u = 0; u < 4; ++u) {
            int idx = (int)((a4 >> (16 * u)) & 0xFFFFu) + (int)((b4 >> (8 * u)) & 0xFFu);
            float v = b2f(T1[idx]) + b2f(T2[idx]);
            outw |= (uint64_t)f2b(v) << (16 * u);
        }
        *(uint64_t*)&Sh[pr * 520 + p] = outw;
    }
    __syncthreads();

    int wid = t >> 6, lane = t & 63;
    int lr = lane & 31, hf = lane >> 5;
    int n_base = wid * 128;

    const unsigned short* Sa = &Sh[lr * 520 + hf * 8];
    const unsigned short* Bz0 = wswz + (size_t)((wid * 4 + 0) * 32) * 512 + lane * 8;
    const unsigned short* Bz1 = wswz + (size_t)((wid * 4 + 1) * 32) * 512 + lane * 8;
    const unsigned short* Bz2 = wswz + (size_t)((wid * 4 + 2) * 32) * 512 + lane * 8;
    const unsigned short* Bz3 = wswz + (size_t)((wid * 4 + 3) * 32) * 512 + lane * 8;

    f32x16 acc0, acc1, acc2, acc3;
#pragma unroll
    for (int j = 0; j < 16; ++j) { acc0[j] = 0.f; acc1[j] = 0.f; acc2[j] = 0.f; acc3[j] = 0.f; }

#pragma unroll 2
    for (int kt = 0; kt < 32; ++kt) {
        bf16x8 av = *(const bf16x8*)(Sa + kt * 16);
        bf16x8 bv0 = *(const bf16x8*)(Bz0 + kt * 512);
        bf16x8 bv1 = *(const bf16x8*)(Bz1 + kt * 512);
        bf16x8 bv2 = *(const bf16x8*)(Bz2 + kt * 512);
        bf16x8 bv3 = *(const bf16x8*)(Bz3 + kt * 512);
        acc0 = __builtin_amdgcn_mfma_f32_32x32x16_bf16(av, bv0, acc0, 0, 0, 0);
        acc1 = __builtin_amdgcn_mfma_f32_32x32x16_bf16(av, bv1, acc1, 0, 0, 0);
        acc2 = __builtin_amdgcn_mfma_f32_32x32x16_bf16(av, bv2, acc2, 0, 0, 0);
        acc3 = __builtin_amdgcn_mfma_f32_32x32x16_bf16(av, bv3, acc3, 0, 0, 0);
    }

    float prow[16];
#pragma unroll
    for (int r = 0; r < 16; ++r) prow[r] = 0.f;
#pragma unroll
    for (int r = 0; r < 16; ++r) {
        int row = (r & 3) + 8 * (r >> 2) + 4 * hf;
        prow[r] += acc0[r] * b2f(Sh[row * 520 + (n_base +  0 + lr)]);
        prow[r] += acc1[r] * b2f(Sh[row * 520 + (n_base + 32 + lr)]);
        prow[r] += acc2[r] * b2f(Sh[row * 520 + (n_base + 64 + lr)]);
        prow[r] += acc3[r] * b2f(Sh[row * 520 + (n_base + 96 + lr)]);
    }
#pragma unroll
    for (int r = 0; r < 16; ++r) {
        float v = prow[r];
        v += __shfl_xor(v, 1);
        v += __shfl_xor(v, 2);
        v += __shfl_xor(v, 4);
        v += __shfl_xor(v, 8);
        v += __shfl_xor(v, 16);
        if (lr == 0) {
            int row = (r & 3) + 8 * (r >> 2) + 4 * hf;
            Kacc[wid][row] = v;
        }
    }
    __syncthreads();

    if (t < 32) {
        float K = Kacc[0][t] + Kacc[1][t] + Kacc[2][t] + Kacc[3][t];
        int ti = t >> 3, tj = t & 7;
        int i = i0 + ti, j = j0 + tj;
        float a0 = Ainp[0];
        out[i * 256 + j] = a0 * a0 * K * kinv[i] * kinv[256 + j];
    }
}

// ---------------- launcher ----------------
extern "C" void kernel_launch(void* const* d_in, const int* in_sizes, int n_in,
                              void* d_out, int out_size, void* d_ws, size_t ws_size,
                              hipStream_t stream) {
    const int*   X1 = (const int*)d_in[0];
    const int*   X2 = (const int*)d_in[1];
    const float* W  = (const float*)d_in[2];
    const float* b  = (const float*)d_in[3];
    const float* wp = (const float*)d_in[4];
    const float* a  = (const float*)d_in[5];
    float* out = (float*)d_out;

    char* ws = (char*)d_ws;
    float*          E     = (float*)(ws + 0);                 // 5,505,024
    float*          T     = (float*)(ws + 5505024);           //   917,504
    float*          w32   = (float*)(ws + 6422528);           // 1,048,576
    unsigned short* wswz  = (unsigned short*)(ws + 7471104);  //   524,288
    float*          kinv  = (float*)(ws + 7995392);           //     2,048
    uint8_t*        X8    = (uint8_t*)(ws + 7997440);         //   262,144
    uint32_t*       Abits = (uint32_t*)(ws + 8259584);        //   688,128  (end 8,947,712)
    unsigned short* Wbz   = (unsigned short*)(ws + 8947712);  // 57,802,752 (end 66,750,464)

    prep_kernel<<<PB_TOTAL, 256, 0, stream>>>(X1, X2, W, b, wp, X8, Abits, w32, wswz, E, Wbz);
    e_mfma_bz_kernel<<<dim3(21, 2, ZCH), 256, 0, stream>>>(Abits, Wbz, E);
    t_kernel<<<512, 256, 0, stream>>>(E, T);
    k_kernel<<<128, 256, 0, stream>>>(X8, T, w32, kinv);
    k4_kernel<<<dim3(64, 32), 256, 0, stream>>>(X8, T, wswz, kinv, a, out);
}